// Round 10
// baseline (86.307 us; speedup 1.0000x reference)
//
#include <hip/hip_runtime.h>
#include <hip/hip_bf16.h>

#define STUN   50000
#define BATCH  4096
#define LOG2E  1.4426950408889634f

__device__ __forceinline__ float fexp2(float x){ return __builtin_amdgcn_exp2f(x); }
__device__ __forceinline__ float frcp (float x){ return __builtin_amdgcn_rcpf(x); }
__device__ __forceinline__ float fsig (float x){ return frcp(1.0f + fexp2(-LOG2E * x)); }

// ---------------------------------------------------------------------------
// K0: weight repack (float4-interleaved) + E-matrix precompute (interleaved).
//   kle4 [u4=16][idx=128][4]  = kle[idx][u4*4+c]
//   fc1i/fc2i [u4=48][128][4] = fcW[idx][u4*4+c]
//   W1ai/W2ai [u4=32][128][4] = W[idx][u4*4+c]        (the 'a' half, u<128)
//   E1i/E2i  [j4=32][k=128][4]= exp2(-log2e * sum_t kle[k][t]*W[j4*4+c][128+t])
// ---------------------------------------------------------------------------
__global__ __launch_bounds__(128) void k_pre(
    const float* __restrict__ kle,
    const float* __restrict__ W1,
    const float* __restrict__ W2,
    const float* __restrict__ fc1_W,
    const float* __restrict__ fc2_W,
    float* __restrict__ kle4,
    float* __restrict__ fc1i,
    float* __restrict__ fc2i,
    float* __restrict__ W1ai,
    float* __restrict__ W2ai,
    float* __restrict__ E1i,
    float* __restrict__ E2i)
{
    const int bid = blockIdx.x;
    const int t   = threadIdx.x;   // 0..127
    if (bid < 16) {
        const int u4 = bid;
        float4 v;
        v.x = kle[t * 64 + u4 * 4 + 0];
        v.y = kle[t * 64 + u4 * 4 + 1];
        v.z = kle[t * 64 + u4 * 4 + 2];
        v.w = kle[t * 64 + u4 * 4 + 3];
        *(float4*)&kle4[(u4 * 128 + t) * 4] = v;
    } else if (bid < 64) {
        const int u4 = bid - 16;
        float4 v;
        v.x = fc1_W[t * 192 + u4 * 4 + 0];
        v.y = fc1_W[t * 192 + u4 * 4 + 1];
        v.z = fc1_W[t * 192 + u4 * 4 + 2];
        v.w = fc1_W[t * 192 + u4 * 4 + 3];
        *(float4*)&fc1i[(u4 * 128 + t) * 4] = v;
    } else if (bid < 112) {
        const int u4 = bid - 64;
        float4 v;
        v.x = fc2_W[t * 192 + u4 * 4 + 0];
        v.y = fc2_W[t * 192 + u4 * 4 + 1];
        v.z = fc2_W[t * 192 + u4 * 4 + 2];
        v.w = fc2_W[t * 192 + u4 * 4 + 3];
        *(float4*)&fc2i[(u4 * 128 + t) * 4] = v;
    } else if (bid < 144) {
        const int u4 = bid - 112;
        float4 v;
        v.x = W1[t * 192 + u4 * 4 + 0];
        v.y = W1[t * 192 + u4 * 4 + 1];
        v.z = W1[t * 192 + u4 * 4 + 2];
        v.w = W1[t * 192 + u4 * 4 + 3];
        *(float4*)&W1ai[(u4 * 128 + t) * 4] = v;
    } else if (bid < 176) {
        const int u4 = bid - 144;
        float4 v;
        v.x = W2[t * 192 + u4 * 4 + 0];
        v.y = W2[t * 192 + u4 * 4 + 1];
        v.z = W2[t * 192 + u4 * 4 + 2];
        v.w = W2[t * 192 + u4 * 4 + 3];
        *(float4*)&W2ai[(u4 * 128 + t) * 4] = v;
    } else if (bid < 304) {
        const int j = bid - 176;          // lane t = k
        float acc = 0.f;
        #pragma unroll
        for (int u4 = 0; u4 < 16; ++u4) {
            const float4 kv = *(const float4*)&kle[t * 64 + u4 * 4];
            const float4 wv = *(const float4*)&W1[j * 192 + 128 + u4 * 4];
            acc += kv.x * wv.x + kv.y * wv.y + kv.z * wv.z + kv.w * wv.w;
        }
        E1i[((j >> 2) * 128 + t) * 4 + (j & 3)] = fexp2(-LOG2E * acc);
    } else {
        const int j = bid - 304;
        float acc = 0.f;
        #pragma unroll
        for (int u4 = 0; u4 < 16; ++u4) {
            const float4 kv = *(const float4*)&kle[t * 64 + u4 * 4];
            const float4 wv = *(const float4*)&W2[j * 192 + 128 + u4 * 4];
            acc += kv.x * wv.x + kv.y * wv.y + kv.z * wv.z + kv.w * wv.w;
        }
        E2i[((j >> 2) * 128 + t) * 4 + (j & 3)] = fexp2(-LOG2E * acc);
    }
}

// ---------------------------------------------------------------------------
// K_G: gather -> xg[b][256] = {stu_row(64), sig(kd)(64), p_stu(64), sig(pe)(64)}
// grid 512 x 512 thr: 8 b/block, 64 u-lanes each.
// ---------------------------------------------------------------------------
__global__ __launch_bounds__(512) void k_g(
    const int*   __restrict__ stu_id,
    const int*   __restrict__ exer_id,
    const float* __restrict__ student_emb,
    const float* __restrict__ prompt_stu,
    const float* __restrict__ k_diff,
    const float* __restrict__ s_exer,
    float* __restrict__ xg)
{
    const int t = threadIdx.x;
    const int b = blockIdx.x * 8 + (t >> 6);
    const int u = t & 63;
    const int sid = stu_id[b];
    const int eid = exer_id[b];
    const int er  = (eid >= 10000) ? 1 : 0;
    float* xb = xg + b * 256;
    xb[u]       = student_emb[sid * 64 + u];
    xb[64 + u]  = fsig(k_diff[eid * 64 + u]);
    xb[128 + u] = prompt_stu[(sid % STUN) * 64 + u];
    xb[192 + u] = fsig(s_exer[er * 64 + u]);
}

#define STEP4(A, W, X) { \
    A = fmaf((W).x, (X).x, A); A = fmaf((W).y, (X).y, A); \
    A = fmaf((W).z, (X).z, A); A = fmaf((W).w, (X).w, A); }

// ---------------------------------------------------------------------------
// K_OLD: old[b][half*128+idx] = sig( dot(x_half[b], kle[idx]) )
// grid 2048 = (bq, half) x 128 thr. x uniform (s_load), weights per-lane.
// ---------------------------------------------------------------------------
__global__ __launch_bounds__(128) void k_old(
    const float* __restrict__ xg,
    const float* __restrict__ kle4,
    float* __restrict__ old_g)
{
    const int half = blockIdx.x & 1;
    const int b0   = (blockIdx.x >> 1) * 4;
    const int idx  = threadIdx.x;
    const float* xb0 = xg + (b0 + 0) * 256 + half * 64;
    const float* xb1 = xg + (b0 + 1) * 256 + half * 64;
    const float* xb2 = xg + (b0 + 2) * 256 + half * 64;
    const float* xb3 = xg + (b0 + 3) * 256 + half * 64;
    float a0 = 0.f, a1 = 0.f, a2 = 0.f, a3 = 0.f;
    #pragma unroll 4
    for (int u4 = 0; u4 < 16; ++u4) {
        const float4 w  = *(const float4*)&kle4[(u4 * 128 + idx) * 4];
        const float4 x0 = *(const float4*)&xb0[u4 * 4];
        const float4 x1 = *(const float4*)&xb1[u4 * 4];
        const float4 x2 = *(const float4*)&xb2[u4 * 4];
        const float4 x3 = *(const float4*)&xb3[u4 * 4];
        STEP4(a0, w, x0); STEP4(a1, w, x1); STEP4(a2, w, x2); STEP4(a3, w, x3);
    }
    const int o = half * 128 + idx;
    old_g[(b0 + 0) * 256 + o] = fsig(a0);
    old_g[(b0 + 1) * 256 + o] = fsig(a1);
    old_g[(b0 + 2) * 256 + o] = fsig(a2);
    old_g[(b0 + 3) * 256 + o] = fsig(a3);
}

// ---------------------------------------------------------------------------
// K_E: e[b][half*128+idx] = sig( [p, old] @ fcW[idx] + fcb[idx] )
// grid 2048 = (bq, half) x 128 thr.
// ---------------------------------------------------------------------------
__global__ __launch_bounds__(128) void k_e(
    const float* __restrict__ xg,
    const float* __restrict__ old_g,
    const float* __restrict__ fc1i,
    const float* __restrict__ fc2i,
    const float* __restrict__ fc1_b,
    const float* __restrict__ fc2_b,
    float* __restrict__ e_g)
{
    const int half = blockIdx.x & 1;
    const int b0   = (blockIdx.x >> 1) * 4;
    const int idx  = threadIdx.x;
    const float* fcT = half ? fc2i : fc1i;
    const float* pb0 = xg + (b0 + 0) * 256 + 128 + half * 64;
    const float* pb1 = xg + (b0 + 1) * 256 + 128 + half * 64;
    const float* pb2 = xg + (b0 + 2) * 256 + 128 + half * 64;
    const float* pb3 = xg + (b0 + 3) * 256 + 128 + half * 64;
    const float* ob0 = old_g + (b0 + 0) * 256 + half * 128;
    const float* ob1 = old_g + (b0 + 1) * 256 + half * 128;
    const float* ob2 = old_g + (b0 + 2) * 256 + half * 128;
    const float* ob3 = old_g + (b0 + 3) * 256 + half * 128;
    float a0 = 0.f, a1 = 0.f, a2 = 0.f, a3 = 0.f;
    #pragma unroll 4
    for (int u4 = 0; u4 < 16; ++u4) {
        const float4 w  = *(const float4*)&fcT[(u4 * 128 + idx) * 4];
        const float4 x0 = *(const float4*)&pb0[u4 * 4];
        const float4 x1 = *(const float4*)&pb1[u4 * 4];
        const float4 x2 = *(const float4*)&pb2[u4 * 4];
        const float4 x3 = *(const float4*)&pb3[u4 * 4];
        STEP4(a0, w, x0); STEP4(a1, w, x1); STEP4(a2, w, x2); STEP4(a3, w, x3);
    }
    #pragma unroll 4
    for (int u4 = 16; u4 < 48; ++u4) {
        const float4 w  = *(const float4*)&fcT[(u4 * 128 + idx) * 4];
        const float4 x0 = *(const float4*)&ob0[(u4 - 16) * 4];
        const float4 x1 = *(const float4*)&ob1[(u4 - 16) * 4];
        const float4 x2 = *(const float4*)&ob2[(u4 - 16) * 4];
        const float4 x3 = *(const float4*)&ob3[(u4 - 16) * 4];
        STEP4(a0, w, x0); STEP4(a1, w, x1); STEP4(a2, w, x2); STEP4(a3, w, x3);
    }
    const float bias = (half ? fc2_b : fc1_b)[idx];
    const int o = half * 128 + idx;
    e_g[(b0 + 0) * 256 + o] = fsig(a0 + bias);
    e_g[(b0 + 1) * 256 + o] = fsig(a1 + bias);
    e_g[(b0 + 2) * 256 + o] = fsig(a2 + bias);
    e_g[(b0 + 3) * 256 + o] = fsig(a3 + bias);
}

// ---------------------------------------------------------------------------
// K_ES: es[b][half*128+j] = exp2( -log2e * dot(e_half[b], Wa[j]) )
// grid 2048 = (bq, half) x 128 thr.
// ---------------------------------------------------------------------------
__global__ __launch_bounds__(128) void k_es(
    const float* __restrict__ e_g,
    const float* __restrict__ W1ai,
    const float* __restrict__ W2ai,
    float* __restrict__ es_g)
{
    const int half = blockIdx.x & 1;
    const int b0   = (blockIdx.x >> 1) * 4;
    const int idx  = threadIdx.x;
    const float* WT  = half ? W2ai : W1ai;
    const float* eb0 = e_g + (b0 + 0) * 256 + half * 128;
    const float* eb1 = e_g + (b0 + 1) * 256 + half * 128;
    const float* eb2 = e_g + (b0 + 2) * 256 + half * 128;
    const float* eb3 = e_g + (b0 + 3) * 256 + half * 128;
    float a0 = 0.f, a1 = 0.f, a2 = 0.f, a3 = 0.f;
    #pragma unroll 4
    for (int u4 = 0; u4 < 32; ++u4) {
        const float4 w  = *(const float4*)&WT[(u4 * 128 + idx) * 4];
        const float4 x0 = *(const float4*)&eb0[u4 * 4];
        const float4 x1 = *(const float4*)&eb1[u4 * 4];
        const float4 x2 = *(const float4*)&eb2[u4 * 4];
        const float4 x3 = *(const float4*)&eb3[u4 * 4];
        STEP4(a0, w, x0); STEP4(a1, w, x1); STEP4(a2, w, x2); STEP4(a3, w, x3);
    }
    const int o = half * 128 + idx;
    es_g[(b0 + 0) * 256 + o] = fexp2(-LOG2E * a0);
    es_g[(b0 + 1) * 256 + o] = fexp2(-LOG2E * a1);
    es_g[(b0 + 2) * 256 + o] = fexp2(-LOG2E * a2);
    es_g[(b0 + 3) * 256 + o] = fexp2(-LOG2E * a3);
}

// ---------------------------------------------------------------------------
// K_MAINP: partial accg[b][jh][k] = sum_{j in jh-half} (sig1-sig2)*w3
// grid 2048 = (bq, jh) x 128 thr (t = k). Zero LDS, zero barriers.
// u = es1*E1, v = es2*E2, term = (v-u)*rcp((1+u)(1+v))*w3
// ---------------------------------------------------------------------------
__global__ __launch_bounds__(128) void k_mainp(
    const float* __restrict__ es_g,
    const float* __restrict__ E1i,    // [j4=32][k=128][4]
    const float* __restrict__ E2i,
    const float* __restrict__ W3,
    float* __restrict__ accg)
{
    const int jh = blockIdx.x & 1;
    const int b0 = (blockIdx.x >> 1) * 4;
    const int k  = threadIdx.x;
    const float4* E1v = (const float4*)E1i + jh * 16 * 128 + k;
    const float4* E2v = (const float4*)E2i + jh * 16 * 128 + k;
    const float* s1b0 = es_g + (b0 + 0) * 256 + jh * 64;
    const float* s1b1 = es_g + (b0 + 1) * 256 + jh * 64;
    const float* s1b2 = es_g + (b0 + 2) * 256 + jh * 64;
    const float* s1b3 = es_g + (b0 + 3) * 256 + jh * 64;
    const float* s2b0 = s1b0 + 128;
    const float* s2b1 = s1b1 + 128;
    const float* s2b2 = s1b2 + 128;
    const float* s2b3 = s1b3 + 128;
    const float* w3p  = W3 + jh * 64;

    float a0 = 0.f, a1 = 0.f, a2 = 0.f, a3 = 0.f;

#define COMP(acc, s1c, s2c, e1c, e2c, w3c) { \
        const float uu = (s1c) * (e1c); \
        const float vv = (s2c) * (e2c); \
        const float dd = frcp((1.f + uu) * (1.f + vv)); \
        acc = fmaf((vv - uu) * dd, (w3c), acc); }

#define BODY(acc, S1, S2) { \
        const float4 s1 = *(const float4*)&(S1)[j4 * 4]; \
        const float4 s2 = *(const float4*)&(S2)[j4 * 4]; \
        COMP(acc, s1.x, s2.x, e1.x, e2.x, w3.x); \
        COMP(acc, s1.y, s2.y, e1.y, e2.y, w3.y); \
        COMP(acc, s1.z, s2.z, e1.z, e2.z, w3.z); \
        COMP(acc, s1.w, s2.w, e1.w, e2.w, w3.w); }

    #pragma unroll 4
    for (int j4 = 0; j4 < 16; ++j4) {
        const float4 e1 = E1v[j4 * 128];
        const float4 e2 = E2v[j4 * 128];
        const float4 w3 = *(const float4*)&w3p[j4 * 4];
        BODY(a0, s1b0, s2b0);
        BODY(a1, s1b1, s2b1);
        BODY(a2, s1b2, s2b2);
        BODY(a3, s1b3, s2b3);
    }
#undef BODY
#undef COMP

    accg[((b0 + 0) * 2 + jh) * 128 + k] = a0;
    accg[((b0 + 1) * 2 + jh) * 128 + k] = a1;
    accg[((b0 + 2) * 2 + jh) * 128 + k] = a2;
    accg[((b0 + 3) * 2 + jh) * 128 + k] = a3;
}

// ---------------------------------------------------------------------------
// K_FIN: out[b] = sum_k kn*sig(acc+b3) / sum_k kn. grid 1024 x 128 thr.
// ---------------------------------------------------------------------------
__global__ __launch_bounds__(128) void k_fin(
    const float* __restrict__ accg,
    const float* __restrict__ b3,
    const float* __restrict__ kn,
    float* __restrict__ out)
{
    __shared__ float r[2][4][2];
    const int t  = threadIdx.x;           // k = t, 2 waves
    const int b0 = blockIdx.x * 4;
    const float bb3 = b3[0];
    float co[4], ck[4];
    #pragma unroll
    for (int i = 0; i < 4; ++i) {
        const int b = b0 + i;
        const float acc = accg[(b * 2 + 0) * 128 + t] + accg[(b * 2 + 1) * 128 + t];
        const float o   = fsig(acc + bb3);
        const float knv = kn[b * 128 + t];
        co[i] = o * knv;
        ck[i] = knv;
    }
    #pragma unroll
    for (int off = 1; off < 64; off <<= 1) {
        #pragma unroll
        for (int i = 0; i < 4; ++i) {
            co[i] += __shfl_xor(co[i], off);
            ck[i] += __shfl_xor(ck[i], off);
        }
    }
    if ((t & 63) == 0) {
        const int wid = t >> 6;
        #pragma unroll
        for (int i = 0; i < 4; ++i) {
            r[wid][i][0] = co[i];
            r[wid][i][1] = ck[i];
        }
    }
    __syncthreads();
    if (t < 4)
        out[b0 + t] = (r[0][t][0] + r[1][t][0]) / (r[0][t][1] + r[1][t][1]);
}

// ---------------------------------------------------------------------------
extern "C" void kernel_launch(void* const* d_in, const int* in_sizes, int n_in,
                              void* d_out, int out_size, void* d_ws, size_t ws_size,
                              hipStream_t stream)
{
    const int*   stu_id      = (const int*)  d_in[0];
    const int*   exer_id     = (const int*)  d_in[1];
    const float* kn_emb      = (const float*)d_in[2];
    const float* student_emb = (const float*)d_in[3];
    const float* prompt_stu  = (const float*)d_in[4];
    const float* kle         = (const float*)d_in[5];
    const float* k_diff      = (const float*)d_in[6];
    const float* s_exer      = (const float*)d_in[7];
    const float* W1          = (const float*)d_in[8];
    const float* W2          = (const float*)d_in[9];
    const float* W3          = (const float*)d_in[10];
    const float* b3          = (const float*)d_in[11];
    const float* fc1_W       = (const float*)d_in[12];
    const float* fc1_b       = (const float*)d_in[13];
    const float* fc2_W       = (const float*)d_in[14];
    const float* fc2_b       = (const float*)d_in[15];
    float* out = (float*)d_out;

    float* ws    = (float*)d_ws;
    float* kle4  = ws;                       // 16*128*4   =   8192
    float* fc1i  = kle4  + 8192;             // 48*128*4   =  24576
    float* fc2i  = fc1i  + 24576;
    float* W1ai  = fc2i  + 24576;            // 32*128*4   =  16384
    float* W2ai  = W1ai  + 16384;
    float* E1i   = W2ai  + 16384;            // 32*128*4   =  16384
    float* E2i   = E1i   + 16384;
    float* xg    = E2i   + 16384;            // 4096*256   = 1048576
    float* old_g = xg    + 1048576;
    float* e_g   = old_g + 1048576;
    float* es_g  = e_g   + 1048576;
    float* accg  = es_g  + 1048576;          // 4096*2*128 = 1048576

    k_pre  <<<432, 128, 0, stream>>>(kle, W1, W2, fc1_W, fc2_W,
                                     kle4, fc1i, fc2i, W1ai, W2ai, E1i, E2i);
    k_g    <<<BATCH / 8, 512, 0, stream>>>(stu_id, exer_id, student_emb,
                                           prompt_stu, k_diff, s_exer, xg);
    k_old  <<<(BATCH / 4) * 2, 128, 0, stream>>>(xg, kle4, old_g);
    k_e    <<<(BATCH / 4) * 2, 128, 0, stream>>>(xg, old_g, fc1i, fc2i,
                                                 fc1_b, fc2_b, e_g);
    k_es   <<<(BATCH / 4) * 2, 128, 0, stream>>>(e_g, W1ai, W2ai, es_g);
    k_mainp<<<(BATCH / 4) * 2, 128, 0, stream>>>(es_g, E1i, E2i, W3, accg);
    k_fin  <<<BATCH / 4, 128, 0, stream>>>(accg, b3, kn_emb, out);
}

// Round 11
// 58.433 us; speedup vs baseline: 1.4770x; 1.4770x over previous
//
#include <hip/hip_runtime.h>
#include <hip/hip_bf16.h>

#define STUN   50000
#define BATCH  4096
#define LOG2E  1.4426950408889634f

__device__ __forceinline__ float fexp2(float x){ return __builtin_amdgcn_exp2f(x); }
__device__ __forceinline__ float frcp (float x){ return __builtin_amdgcn_rcpf(x); }
__device__ __forceinline__ float fsig (float x){ return frcp(1.0f + fexp2(-LOG2E * x)); }

// ---------------------------------------------------------------------------
// K0: weight repack (float4-interleaved) + E-matrix precompute (interleaved).
//   kle4 [u4=16][idx=128][4]  = kle[idx][u4*4+c]
//   fc1i/fc2i [u4=48][128][4] = fcW[idx][u4*4+c]
//   W1ai/W2ai [u4=32][128][4] = W[idx][u4*4+c]        (the 'a' half, u<128)
//   E1i/E2i  [j4=32][k=128][4]= exp2(-log2e * sum_t kle[k][t]*W[j4*4+c][128+t])
// ---------------------------------------------------------------------------
__global__ __launch_bounds__(128) void k_pre(
    const float* __restrict__ kle,
    const float* __restrict__ W1,
    const float* __restrict__ W2,
    const float* __restrict__ fc1_W,
    const float* __restrict__ fc2_W,
    float* __restrict__ kle4,
    float* __restrict__ fc1i,
    float* __restrict__ fc2i,
    float* __restrict__ W1ai,
    float* __restrict__ W2ai,
    float* __restrict__ E1i,
    float* __restrict__ E2i)
{
    const int bid = blockIdx.x;
    const int t   = threadIdx.x;   // 0..127
    if (bid < 16) {
        const int u4 = bid;
        float4 v;
        v.x = kle[t * 64 + u4 * 4 + 0];
        v.y = kle[t * 64 + u4 * 4 + 1];
        v.z = kle[t * 64 + u4 * 4 + 2];
        v.w = kle[t * 64 + u4 * 4 + 3];
        *(float4*)&kle4[(u4 * 128 + t) * 4] = v;
    } else if (bid < 64) {
        const int u4 = bid - 16;
        float4 v;
        v.x = fc1_W[t * 192 + u4 * 4 + 0];
        v.y = fc1_W[t * 192 + u4 * 4 + 1];
        v.z = fc1_W[t * 192 + u4 * 4 + 2];
        v.w = fc1_W[t * 192 + u4 * 4 + 3];
        *(float4*)&fc1i[(u4 * 128 + t) * 4] = v;
    } else if (bid < 112) {
        const int u4 = bid - 64;
        float4 v;
        v.x = fc2_W[t * 192 + u4 * 4 + 0];
        v.y = fc2_W[t * 192 + u4 * 4 + 1];
        v.z = fc2_W[t * 192 + u4 * 4 + 2];
        v.w = fc2_W[t * 192 + u4 * 4 + 3];
        *(float4*)&fc2i[(u4 * 128 + t) * 4] = v;
    } else if (bid < 144) {
        const int u4 = bid - 112;
        float4 v;
        v.x = W1[t * 192 + u4 * 4 + 0];
        v.y = W1[t * 192 + u4 * 4 + 1];
        v.z = W1[t * 192 + u4 * 4 + 2];
        v.w = W1[t * 192 + u4 * 4 + 3];
        *(float4*)&W1ai[(u4 * 128 + t) * 4] = v;
    } else if (bid < 176) {
        const int u4 = bid - 144;
        float4 v;
        v.x = W2[t * 192 + u4 * 4 + 0];
        v.y = W2[t * 192 + u4 * 4 + 1];
        v.z = W2[t * 192 + u4 * 4 + 2];
        v.w = W2[t * 192 + u4 * 4 + 3];
        *(float4*)&W2ai[(u4 * 128 + t) * 4] = v;
    } else if (bid < 304) {
        const int j = bid - 176;          // lane t = k
        float acc = 0.f;
        #pragma unroll
        for (int u4 = 0; u4 < 16; ++u4) {
            const float4 kv = *(const float4*)&kle[t * 64 + u4 * 4];
            const float4 wv = *(const float4*)&W1[j * 192 + 128 + u4 * 4];
            acc += kv.x * wv.x + kv.y * wv.y + kv.z * wv.z + kv.w * wv.w;
        }
        E1i[((j >> 2) * 128 + t) * 4 + (j & 3)] = fexp2(-LOG2E * acc);
    } else {
        const int j = bid - 304;
        float acc = 0.f;
        #pragma unroll
        for (int u4 = 0; u4 < 16; ++u4) {
            const float4 kv = *(const float4*)&kle[t * 64 + u4 * 4];
            const float4 wv = *(const float4*)&W2[j * 192 + 128 + u4 * 4];
            acc += kv.x * wv.x + kv.y * wv.y + kv.z * wv.z + kv.w * wv.w;
        }
        E2i[((j >> 2) * 128 + t) * 4 + (j & 3)] = fexp2(-LOG2E * acc);
    }
}

// ---------------------------------------------------------------------------
// K_PREP: 8 batch elems/block, 512 threads, grid 512 (r8-proven structure).
// ug = t>>8 splits the u-accumulation range; ug1 writes partials to ps[],
// ug0 combines + sigmoid. Output: es_g[b][half*128+j] = exp2(-log2e*s[b][j])
// ---------------------------------------------------------------------------
__global__ __launch_bounds__(512, 4) void k_prep(
    const int*   __restrict__ stu_id,
    const int*   __restrict__ exer_id,
    const float* __restrict__ student_emb,   // (2*50000, 64) flat
    const float* __restrict__ prompt_stu,    // (50000, 64)
    const float* __restrict__ k_diff,        // (20000, 64)
    const float* __restrict__ s_exer,        // (2, 64)
    const float* __restrict__ kle4,
    const float* __restrict__ fc1i,
    const float* __restrict__ fc2i,
    const float* __restrict__ W1ai,
    const float* __restrict__ W2ai,
    const float* __restrict__ fc1_b,
    const float* __restrict__ fc2_b,
    float* __restrict__ es_g)                // (B,256)
{
    __shared__ __align__(16) float sh_in [4][64][8];    // 8 KB
    __shared__ __align__(16) float sh_old[2][128][8];   // 8 KB
    __shared__ __align__(16) float sh_e  [2][128][8];   // 8 KB
    __shared__ __align__(16) float ps    [2][8][128];   // 8 KB  [half][b][idx]

    const int t  = threadIdx.x;           // 0..511
    const int b0 = blockIdx.x * 8;

    // ---- gather phase: 64 threads per local batch elem, coalesced ----
    {
        const int g   = t >> 6;
        const int u   = t & 63;
        const int sid = stu_id[b0 + g];
        const int eid = exer_id[b0 + g];
        const int er  = (eid >= 10000) ? 1 : 0;
        sh_in[0][u][g] = student_emb[sid * 64 + u];
        sh_in[1][u][g] = fsig(k_diff[eid * 64 + u]);
        sh_in[2][u][g] = prompt_stu[(sid % STUN) * 64 + u];
        sh_in[3][u][g] = fsig(s_exer[er * 64 + u]);
    }
    __syncthreads();

    const int ug   = t >> 8;              // u-range group
    const int tt   = t & 255;
    const int half = tt >> 7;
    const int idx  = tt & 127;

    float acc[8];

#define FMA8(xbase) { \
        const float4 x0 = *(const float4*)&(xbase)[0]; \
        const float4 x1 = *(const float4*)&(xbase)[4]; \
        acc[0] += wv * x0.x; acc[1] += wv * x0.y; acc[2] += wv * x0.z; acc[3] += wv * x0.w; \
        acc[4] += wv * x1.x; acc[5] += wv * x1.y; acc[6] += wv * x1.z; acc[7] += wv * x1.w; }

#define WSTEP(WARR, XARR, u4) { \
        const float4 w4 = *(const float4*)&WARR[((u4) * 128 + idx) * 4]; \
        { const float wv = w4.x; FMA8(XARR[(u4)*4+0]); } \
        { const float wv = w4.y; FMA8(XARR[(u4)*4+1]); } \
        { const float wv = w4.z; FMA8(XARR[(u4)*4+2]); } \
        { const float wv = w4.w; FMA8(XARR[(u4)*4+3]); } }

#define WSTEPO(WARR, XARR, u4, uoff) { \
        const float4 w4 = *(const float4*)&WARR[((u4) * 128 + idx) * 4]; \
        { const float wv = w4.x; FMA8(XARR[((u4)-(uoff))*4+0]); } \
        { const float wv = w4.y; FMA8(XARR[((u4)-(uoff))*4+1]); } \
        { const float wv = w4.z; FMA8(XARR[((u4)-(uoff))*4+2]); } \
        { const float wv = w4.w; FMA8(XARR[((u4)-(uoff))*4+3]); } }

    // ---- stage 1: old[k] = sig( dot(row, kle[k]) ), u-split ----
    #pragma unroll
    for (int b = 0; b < 8; ++b) acc[b] = 0.f;
    {
        const int u4a = ug * 8;
        #pragma unroll 4
        for (int u4 = u4a; u4 < u4a + 8; ++u4) WSTEP(kle4, sh_in[half], u4);
    }
    if (ug == 1) {
        #pragma unroll
        for (int b = 0; b < 8; ++b) ps[half][b][idx] = acc[b];
    }
    __syncthreads();
    if (ug == 0) {
        #pragma unroll
        for (int b = 0; b < 8; ++b)
            sh_old[half][idx][b] = fsig(acc[b] + ps[half][b][idx]);
    }
    __syncthreads();

    // ---- stage 2: e[i] = sig( [p, old] @ fcW[i] + fcb[i] ), u-split ----
    #pragma unroll
    for (int b = 0; b < 8; ++b) acc[b] = 0.f;
    {
        const float* fcT = half ? fc2i : fc1i;
        if (ug == 0) {
            #pragma unroll 4
            for (int u4 = 0; u4 < 16; ++u4) WSTEP(fcT, sh_in[2 + half], u4);
            #pragma unroll 4
            for (int u4 = 16; u4 < 24; ++u4) WSTEPO(fcT, sh_old[half], u4, 16);
        } else {
            #pragma unroll 4
            for (int u4 = 24; u4 < 48; ++u4) WSTEPO(fcT, sh_old[half], u4, 16);
        }
    }
    if (ug == 1) {
        #pragma unroll
        for (int b = 0; b < 8; ++b) ps[half][b][idx] = acc[b];
    }
    __syncthreads();
    if (ug == 0) {
        const float bias = (half ? fc2_b : fc1_b)[idx];
        #pragma unroll
        for (int b = 0; b < 8; ++b)
            sh_e[half][idx][b] = fsig(acc[b] + ps[half][b][idx] + bias);
    }
    __syncthreads();

    // ---- stage 3: es[j] = exp2(-log2e * dot(e, Wa[j])), u-split -> global ----
    #pragma unroll
    for (int b = 0; b < 8; ++b) acc[b] = 0.f;
    {
        const float* WT = half ? W2ai : W1ai;
        const int u4a = ug * 16;
        #pragma unroll 4
        for (int u4 = u4a; u4 < u4a + 16; ++u4) WSTEP(WT, sh_e[half], u4);
    }
    if (ug == 1) {
        #pragma unroll
        for (int b = 0; b < 8; ++b) ps[half][b][idx] = acc[b];
    }
    __syncthreads();
    if (ug == 0) {
        #pragma unroll
        for (int b = 0; b < 8; ++b)
            es_g[(b0 + b) * 256 + half * 128 + idx] =
                fexp2(-LOG2E * (acc[b] + ps[half][b][idx]));
    }
#undef FMA8
#undef WSTEP
#undef WSTEPO
}

// ---------------------------------------------------------------------------
// K_MAIN v2: LDS-free hot loop + fused finalization.
// 4 batch elems/block, 256 threads, grid 1024 (4 blocks/CU, 16 waves/CU).
// t -> k = t&127, bh = t>>7 picks b-pair {b0+2bh, b0+2bh+1}.
// es/W3/b3: wave-uniform s_load (SMEM pipe). E: per-lane coalesced f4 (L2).
// Per pair: u = es1*E1, v = es2*E2, acc += (v-u)*rcp((1+u)(1+v))*w3.
// ---------------------------------------------------------------------------
__global__ __launch_bounds__(256, 4) void k_main(
    const float* __restrict__ es_g,   // [B][256]: [0..127]=es1, [128..255]=es2
    const float* __restrict__ E1i,    // [j4=32][k=128][4]
    const float* __restrict__ E2i,
    const float* __restrict__ W3,
    const float* __restrict__ b3,
    const float* __restrict__ kn,
    float* __restrict__ out)
{
    __shared__ float r[4][2][2];      // [wave][b-in-pair][{o,k}]

    const int t  = threadIdx.x;       // 0..255
    const int b0 = blockIdx.x * 4;
    const int k  = t & 127;
    const int bh = t >> 7;            // b-pair select
    const int ba = b0 + bh * 2;

    const float4* E1v = (const float4*)E1i + k;
    const float4* E2v = (const float4*)E2i + k;
    const float* s1a = es_g + (ba + 0) * 256;
    const float* s2a = s1a + 128;
    const float* s1b = es_g + (ba + 1) * 256;
    const float* s2b = s1b + 128;

    float acc0 = 0.f, acc1 = 0.f;

#define COMP(acc, s1c, s2c, e1c, e2c, w3c) { \
        const float uu = (s1c) * (e1c); \
        const float vv = (s2c) * (e2c); \
        const float dd = frcp((1.f + uu) * (1.f + vv)); \
        acc = fmaf((vv - uu) * dd, (w3c), acc); }

    #pragma unroll 4
    for (int j4 = 0; j4 < 32; ++j4) {
        const float4 e1  = E1v[j4 * 128];
        const float4 e2  = E2v[j4 * 128];
        const float4 w3  = *(const float4*)&W3[j4 * 4];
        const float4 p1a = *(const float4*)&s1a[j4 * 4];
        const float4 p2a = *(const float4*)&s2a[j4 * 4];
        const float4 p1b = *(const float4*)&s1b[j4 * 4];
        const float4 p2b = *(const float4*)&s2b[j4 * 4];
        COMP(acc0, p1a.x, p2a.x, e1.x, e2.x, w3.x);
        COMP(acc0, p1a.y, p2a.y, e1.y, e2.y, w3.y);
        COMP(acc0, p1a.z, p2a.z, e1.z, e2.z, w3.z);
        COMP(acc0, p1a.w, p2a.w, e1.w, e2.w, w3.w);
        COMP(acc1, p1b.x, p2b.x, e1.x, e2.x, w3.x);
        COMP(acc1, p1b.y, p2b.y, e1.y, e2.y, w3.y);
        COMP(acc1, p1b.z, p2b.z, e1.z, e2.z, w3.z);
        COMP(acc1, p1b.w, p2b.w, e1.w, e2.w, w3.w);
    }
#undef COMP

    // ---- epilogue: outer sigmoid + kn-weighted mean over k ----
    const float bb3 = b3[0];
    const float o0  = fsig(acc0 + bb3);
    const float o1  = fsig(acc1 + bb3);
    const float kn0 = kn[(ba + 0) * 128 + k];
    const float kn1 = kn[(ba + 1) * 128 + k];
    float co0 = o0 * kn0, ck0 = kn0;
    float co1 = o1 * kn1, ck1 = kn1;
    #pragma unroll
    for (int off = 1; off < 64; off <<= 1) {
        co0 += __shfl_xor(co0, off);
        ck0 += __shfl_xor(ck0, off);
        co1 += __shfl_xor(co1, off);
        ck1 += __shfl_xor(ck1, off);
    }
    const int w = t >> 6;             // wave id 0..3
    if ((t & 63) == 0) {
        r[w][0][0] = co0; r[w][0][1] = ck0;
        r[w][1][0] = co1; r[w][1][1] = ck1;
    }
    __syncthreads();
    if (t < 4) {
        // b0+0: waves 0,1 slot 0; b0+1: waves 0,1 slot 1;
        // b0+2: waves 2,3 slot 0; b0+3: waves 2,3 slot 1.
        const int pair = t >> 1;
        const int i    = t & 1;
        const float so = r[pair * 2][i][0] + r[pair * 2 + 1][i][0];
        const float sk = r[pair * 2][i][1] + r[pair * 2 + 1][i][1];
        out[b0 + pair * 2 + i] = so / sk;
    }
}

// ---------------------------------------------------------------------------
extern "C" void kernel_launch(void* const* d_in, const int* in_sizes, int n_in,
                              void* d_out, int out_size, void* d_ws, size_t ws_size,
                              hipStream_t stream)
{
    const int*   stu_id      = (const int*)  d_in[0];
    const int*   exer_id     = (const int*)  d_in[1];
    const float* kn_emb      = (const float*)d_in[2];
    const float* student_emb = (const float*)d_in[3];
    const float* prompt_stu  = (const float*)d_in[4];
    const float* kle         = (const float*)d_in[5];
    const float* k_diff      = (const float*)d_in[6];
    const float* s_exer      = (const float*)d_in[7];
    const float* W1          = (const float*)d_in[8];
    const float* W2          = (const float*)d_in[9];
    const float* W3          = (const float*)d_in[10];
    const float* b3          = (const float*)d_in[11];
    const float* fc1_W       = (const float*)d_in[12];
    const float* fc1_b       = (const float*)d_in[13];
    const float* fc2_W       = (const float*)d_in[14];
    const float* fc2_b       = (const float*)d_in[15];
    float* out = (float*)d_out;

    float* ws   = (float*)d_ws;
    float* kle4 = ws;                        // 16*128*4  = 8192
    float* fc1i = kle4 + 8192;               // 48*128*4  = 24576
    float* fc2i = fc1i + 24576;
    float* W1ai = fc2i + 24576;              // 32*128*4  = 16384
    float* W2ai = W1ai + 16384;
    float* E1i  = W2ai + 16384;              // 32*128*4  = 16384
    float* E2i  = E1i  + 16384;
    float* es_g = E2i  + 16384;              // 4096*256  = 1048576

    k_pre <<<432, 128, 0, stream>>>(kle, W1, W2, fc1_W, fc2_W,
                                    kle4, fc1i, fc2i, W1ai, W2ai, E1i, E2i);
    k_prep<<<BATCH / 8, 512, 0, stream>>>(stu_id, exer_id, student_emb, prompt_stu,
                                          k_diff, s_exer, kle4, fc1i, fc2i,
                                          W1ai, W2ai, fc1_b, fc2_b, es_g);
    k_main<<<BATCH / 4, 256, 0, stream>>>(es_g, E1i, E2i, W3, b3, kn_emb, out);
}

// Round 12
// 48.026 us; speedup vs baseline: 1.7971x; 1.2167x over previous
//
#include <hip/hip_runtime.h>
#include <hip/hip_bf16.h>

#define STUN   50000
#define BATCH  4096
#define LOG2E  1.4426950408889634f

__device__ __forceinline__ float fexp2(float x){ return __builtin_amdgcn_exp2f(x); }
__device__ __forceinline__ float frcp (float x){ return __builtin_amdgcn_rcpf(x); }
__device__ __forceinline__ float fsig (float x){ return frcp(1.0f + fexp2(-LOG2E * x)); }

// ---------------------------------------------------------------------------
// K0: transposes + E-matrix precompute. 960 blocks x 128 threads.
//   kleT  [u=64][idx=128]  = kle[idx][u]
//   fc1T/fc2T [u=192][128] = fcW[idx][u]
//   W1aT/W2aT [u=128][128] = W[idx][u]          (the 'a' half, u<128)
//   E1i/E2i [j4=32][k=128][4] = exp2(-log2e * sum_t kle[k][t]*W[j4*4+c][128+t])
// ---------------------------------------------------------------------------
__global__ __launch_bounds__(128) void k_pre(
    const float* __restrict__ kle,
    const float* __restrict__ W1,
    const float* __restrict__ W2,
    const float* __restrict__ fc1_W,
    const float* __restrict__ fc2_W,
    float* __restrict__ kleT,
    float* __restrict__ fc1T,
    float* __restrict__ fc2T,
    float* __restrict__ W1aT,
    float* __restrict__ W2aT,
    float* __restrict__ E1i,
    float* __restrict__ E2i)
{
    const int bid = blockIdx.x;
    const int t   = threadIdx.x;   // 0..127
    if (bid < 64) {
        const int u = bid;
        kleT[u * 128 + t] = kle[t * 64 + u];
    } else if (bid < 256) {
        const int u = bid - 64;
        fc1T[u * 128 + t] = fc1_W[t * 192 + u];
    } else if (bid < 448) {
        const int u = bid - 256;
        fc2T[u * 128 + t] = fc2_W[t * 192 + u];
    } else if (bid < 576) {
        const int u = bid - 448;
        W1aT[u * 128 + t] = W1[t * 192 + u];
    } else if (bid < 704) {
        const int u = bid - 576;
        W2aT[u * 128 + t] = W2[t * 192 + u];
    } else if (bid < 832) {
        const int j = bid - 704;          // lane t = k
        float acc = 0.f;
        #pragma unroll
        for (int u4 = 0; u4 < 16; ++u4) {
            const float4 kv = *(const float4*)&kle[t * 64 + u4 * 4];
            const float4 wv = *(const float4*)&W1[j * 192 + 128 + u4 * 4];
            acc += kv.x * wv.x + kv.y * wv.y + kv.z * wv.z + kv.w * wv.w;
        }
        E1i[((j >> 2) * 128 + t) * 4 + (j & 3)] = fexp2(-LOG2E * acc);
    } else {
        const int j = bid - 832;
        float acc = 0.f;
        #pragma unroll
        for (int u4 = 0; u4 < 16; ++u4) {
            const float4 kv = *(const float4*)&kle[t * 64 + u4 * 4];
            const float4 wv = *(const float4*)&W2[j * 192 + 128 + u4 * 4];
            acc += kv.x * wv.x + kv.y * wv.y + kv.z * wv.z + kv.w * wv.w;
        }
        E2i[((j >> 2) * 128 + t) * 4 + (j & 3)] = fexp2(-LOG2E * acc);
    }
}

// ---------------------------------------------------------------------------
// K_PREP v3: idx-blocked prep. 8 b/block, 256 threads, grid 512.
// Wave wv = u-quarter; lane l: half = l>>5, iq = l&31 -> idx = iq*4+c (c=0..3).
// Each thread: acc[4 idx][8 b]; one LDS x-read feeds 32 FMAs (was 8).
// Partials combined via padded ps[] (stride 36 -> no pathological conflicts).
// Output: es{1,2}o[b][idx] = exp2(-log2e * s)
// ---------------------------------------------------------------------------
__global__ __launch_bounds__(256, 2) void k_prep(
    const int*   __restrict__ stu_id,
    const int*   __restrict__ exer_id,
    const float* __restrict__ student_emb,   // (2*50000, 64) flat
    const float* __restrict__ prompt_stu,    // (50000, 64)
    const float* __restrict__ k_diff,        // (20000, 64)
    const float* __restrict__ s_exer,        // (2, 64)
    const float* __restrict__ kleT,          // (64,128)
    const float* __restrict__ fc1T,          // (192,128)
    const float* __restrict__ fc2T,
    const float* __restrict__ W1aT,          // (128,128)
    const float* __restrict__ W2aT,
    const float* __restrict__ fc1_b,
    const float* __restrict__ fc2_b,
    float* __restrict__ es1o,                // (B,128)
    float* __restrict__ es2o)
{
    __shared__ __align__(16) float sh_in [4][64][8];    //  8 KB [src][u][b]
    __shared__ __align__(16) float sh_old[2][128][12];  // 12 KB (stride 12 pad)
    __shared__ __align__(16) float sh_e  [2][128][12];  // 12 KB
    __shared__ __align__(16) float ps[4][2][32][36];    // 36 KB [ug][half][iq][b*4+c]

    const int t  = threadIdx.x;           // 0..255
    const int b0 = blockIdx.x * 8;

    // ---- gather: 32 threads per local batch elem ----
    {
        const int g   = t >> 5;
        const int l   = t & 31;
        const int sid = stu_id[b0 + g];
        const int eid = exer_id[b0 + g];
        const int er  = (eid >= 10000) ? 1 : 0;
        #pragma unroll
        for (int it = 0; it < 2; ++it) {
            const int u = l + 32 * it;
            sh_in[0][u][g] = student_emb[sid * 64 + u];
            sh_in[1][u][g] = fsig(k_diff[eid * 64 + u]);
            sh_in[2][u][g] = prompt_stu[(sid % STUN) * 64 + u];
            sh_in[3][u][g] = fsig(s_exer[er * 64 + u]);
        }
    }
    __syncthreads();

    const int wv   = t >> 6;              // u-quarter (wave id)
    const int l    = t & 63;
    const int half = l >> 5;
    const int iq   = l & 31;              // idx quad base: idx = iq*4+c
    float* myps = &ps[wv][half][iq][0];

    // combine-phase mapping (all 256 threads)
    const int ch   = t >> 7;
    const int cidx = t & 127;
    const int ciq  = cidx >> 2;
    const int cc   = cidx & 3;

    float a[4][8];

#define CLR { _Pragma("unroll") for (int c = 0; c < 4; ++c) \
              _Pragma("unroll") for (int b = 0; b < 8; ++b) a[c][b] = 0.f; }

#define FMAC(c, wc) { \
    a[c][0] = fmaf(wc, x0.x, a[c][0]); a[c][1] = fmaf(wc, x0.y, a[c][1]); \
    a[c][2] = fmaf(wc, x0.z, a[c][2]); a[c][3] = fmaf(wc, x0.w, a[c][3]); \
    a[c][4] = fmaf(wc, x1.x, a[c][4]); a[c][5] = fmaf(wc, x1.y, a[c][5]); \
    a[c][6] = fmaf(wc, x1.z, a[c][6]); a[c][7] = fmaf(wc, x1.w, a[c][7]); }

#define GSTEP(wp, xp) { \
    const float4 w4 = *(const float4*)(wp); \
    const float4 x0 = *(const float4*)&(xp)[0]; \
    const float4 x1 = *(const float4*)&(xp)[4]; \
    FMAC(0, w4.x); FMAC(1, w4.y); FMAC(2, w4.z); FMAC(3, w4.w); }

#define PSTORE { _Pragma("unroll") for (int b = 0; b < 8; ++b) \
    *(float4*)&myps[b * 4] = make_float4(a[0][b], a[1][b], a[2][b], a[3][b]); }

#define PCOMB(res) float res[8]; \
    _Pragma("unroll") for (int b = 0; b < 8; ++b) \
        res[b] = ps[0][ch][ciq][b * 4 + cc] + ps[1][ch][ciq][b * 4 + cc] \
               + ps[2][ch][ciq][b * 4 + cc] + ps[3][ch][ciq][b * 4 + cc];

    // ---- stage 1: old[idx] = sig( dot64(x_row, kle[idx]) ) ----
    CLR;
    {
        const int u0 = wv * 16;
        #pragma unroll 4
        for (int u = u0; u < u0 + 16; ++u)
            GSTEP(&kleT[u * 128 + iq * 4], sh_in[half][u]);
    }
    PSTORE;
    __syncthreads();
    {
        PCOMB(s);
        #pragma unroll
        for (int b = 0; b < 8; ++b) sh_old[ch][cidx][b] = fsig(s[b]);
    }
    __syncthreads();

    // ---- stage 2: e[idx] = sig( [p, old] @ fcW[idx] + fcb[idx] ) ----
    CLR;
    {
        const float* fcT = half ? fc2T : fc1T;
        const int u0 = wv * 48;
        const int ue_in = (u0 + 48 < 64) ? u0 + 48 : 64;
        #pragma unroll 4
        for (int u = u0; u < ue_in; ++u)
            GSTEP(&fcT[u * 128 + iq * 4], sh_in[2 + half][u]);
        const int us_old = (u0 > 64) ? u0 : 64;
        #pragma unroll 4
        for (int u = us_old; u < u0 + 48; ++u)
            GSTEP(&fcT[u * 128 + iq * 4], sh_old[half][u - 64]);
    }
    PSTORE;
    __syncthreads();
    {
        PCOMB(s);
        const float bias = (ch ? fc2_b : fc1_b)[cidx];
        #pragma unroll
        for (int b = 0; b < 8; ++b) sh_e[ch][cidx][b] = fsig(s[b] + bias);
    }
    __syncthreads();

    // ---- stage 3: es[idx] = exp2( -log2e * dot128(e, Wa[idx]) ) ----
    CLR;
    {
        const float* WT = half ? W2aT : W1aT;
        const int u0 = wv * 32;
        #pragma unroll 4
        for (int u = u0; u < u0 + 32; ++u)
            GSTEP(&WT[u * 128 + iq * 4], sh_e[half][u]);
    }
    PSTORE;
    __syncthreads();
    {
        PCOMB(s);
        float* eso = ch ? es2o : es1o;
        #pragma unroll
        for (int b = 0; b < 8; ++b)
            eso[(b0 + b) * 128 + cidx] = fexp2(-LOG2E * s[b]);
    }
#undef CLR
#undef FMAC
#undef GSTEP
#undef PSTORE
#undef PCOMB
}

// ---------------------------------------------------------------------------
// K_MAIN (r8-proven): 2 batch elems/block, 256 threads (4 waves), grid 2048.
// wave w: kh=w&1 (k-half), jh=w>>1 (j-half). Thread: 2 b x 64 j x 1 k.
// Per pair: u = es1*E1, v = es2*E2, acc += (v-u)*rcp((1+u)(1+v))*w3
// ---------------------------------------------------------------------------
__global__ __launch_bounds__(256, 6) void k_main(
    const float* __restrict__ es1o,
    const float* __restrict__ es2o,
    const float* __restrict__ E1i,    // [j4=32][k=128][4] = exp2(A1')
    const float* __restrict__ E2i,
    const float* __restrict__ W3,
    const float* __restrict__ b3,
    const float* __restrict__ kn,
    float* __restrict__ out)
{
    __shared__ __align__(16) float ses[2][2][128];   // [mat][b][j]  2 KB
    __shared__ float sW3[128];
    __shared__ __align__(16) float redj[2][64][2];   // [kh][lane][b] 1 KB
    __shared__ float red2_o[2][2];
    __shared__ float red2_k[2][2];

    const int t   = threadIdx.x;          // 0..255
    const int b0  = blockIdx.x * 2;

    // ---- stage es rows + W3 into LDS ----
    if (t < 128) {
        const int row  = t >> 5;          // 0..3: es1/b0, es1/b1, es2/b0, es2/b1
        const int col4 = (t & 31) * 4;
        const float* src = (row < 2) ? es1o : es2o;
        *(float4*)&ses[row >> 1][row & 1][col4] =
            *(const float4*)&src[(b0 + (row & 1)) * 128 + col4];
    } else if (t < 160) {
        const int q = t - 128;
        *(float4*)&sW3[q * 4] = *(const float4*)&W3[q * 4];
    }
    __syncthreads();

    const int w   = t >> 6;
    const int kk  = t & 63;
    const int kh  = w & 1;
    const int jh  = w >> 1;
    const int k2  = kh * 64 + kk;

    const float4* E1v = (const float4*)E1i;   // [j4*128 + k]
    const float4* E2v = (const float4*)E2i;

    float acc0 = 0.f, acc1 = 0.f;

#define COMP(acc, esv1, esv2, e1c, e2c, w3c) { \
        const float uu = (esv1) * (e1c); \
        const float vv = (esv2) * (e2c); \
        const float dd = frcp((1.f + uu) * (1.f + vv)); \
        acc += ((vv - uu) * dd) * (w3c); }

    #pragma unroll 4
    for (int j4 = 0; j4 < 16; ++j4) {
        const int jj4 = jh * 16 + j4;
        const int j   = jj4 * 4;
        const float4 e1  = E1v[jj4 * 128 + k2];
        const float4 e2  = E2v[jj4 * 128 + k2];
        const float4 w3  = *(const float4*)&sW3[j];
        const float4 s1a = *(const float4*)&ses[0][0][j];
        const float4 s1b = *(const float4*)&ses[0][1][j];
        const float4 s2a = *(const float4*)&ses[1][0][j];
        const float4 s2b = *(const float4*)&ses[1][1][j];

        COMP(acc0, s1a.x, s2a.x, e1.x, e2.x, w3.x);
        COMP(acc0, s1a.y, s2a.y, e1.y, e2.y, w3.y);
        COMP(acc0, s1a.z, s2a.z, e1.z, e2.z, w3.z);
        COMP(acc0, s1a.w, s2a.w, e1.w, e2.w, w3.w);
        COMP(acc1, s1b.x, s2b.x, e1.x, e2.x, w3.x);
        COMP(acc1, s1b.y, s2b.y, e1.y, e2.y, w3.y);
        COMP(acc1, s1b.z, s2b.z, e1.z, e2.z, w3.z);
        COMP(acc1, s1b.w, s2b.w, e1.w, e2.w, w3.w);
    }
#undef COMP

    // ---- epilogue: combine j-halves, outer sigmoid, kn-weighted k-mean ----
    if (jh == 1) {
        redj[kh][kk][0] = acc0;
        redj[kh][kk][1] = acc1;
    }
    __syncthreads();
    if (jh == 0) {
        const float bb3 = b3[0];
        const float t0 = acc0 + redj[kh][kk][0];
        const float t1 = acc1 + redj[kh][kk][1];
        const float o0 = fsig(t0 + bb3);
        const float o1 = fsig(t1 + bb3);
        const float kn0 = kn[(b0 + 0) * 128 + k2];
        const float kn1 = kn[(b0 + 1) * 128 + k2];
        float co0 = o0 * kn0, ck0 = kn0;
        float co1 = o1 * kn1, ck1 = kn1;
        #pragma unroll
        for (int off = 1; off < 64; off <<= 1) {
            co0 += __shfl_xor(co0, off);
            ck0 += __shfl_xor(ck0, off);
            co1 += __shfl_xor(co1, off);
            ck1 += __shfl_xor(ck1, off);
        }
        if (kk == 0) {
            red2_o[kh][0] = co0; red2_o[kh][1] = co1;
            red2_k[kh][0] = ck0; red2_k[kh][1] = ck1;
        }
    }
    __syncthreads();
    if (t < 2) {
        const float so = red2_o[0][t] + red2_o[1][t];
        const float sk = red2_k[0][t] + red2_k[1][t];
        out[b0 + t] = so / sk;
    }
}

// ---------------------------------------------------------------------------
extern "C" void kernel_launch(void* const* d_in, const int* in_sizes, int n_in,
                              void* d_out, int out_size, void* d_ws, size_t ws_size,
                              hipStream_t stream)
{
    const int*   stu_id      = (const int*)  d_in[0];
    const int*   exer_id     = (const int*)  d_in[1];
    const float* kn_emb      = (const float*)d_in[2];
    const float* student_emb = (const float*)d_in[3];
    const float* prompt_stu  = (const float*)d_in[4];
    const float* kle         = (const float*)d_in[5];
    const float* k_diff      = (const float*)d_in[6];
    const float* s_exer      = (const float*)d_in[7];
    const float* W1          = (const float*)d_in[8];
    const float* W2          = (const float*)d_in[9];
    const float* W3          = (const float*)d_in[10];
    const float* b3          = (const float*)d_in[11];
    const float* fc1_W       = (const float*)d_in[12];
    const float* fc1_b       = (const float*)d_in[13];
    const float* fc2_W       = (const float*)d_in[14];
    const float* fc2_b       = (const float*)d_in[15];
    float* out = (float*)d_out;

    float* ws   = (float*)d_ws;
    float* kleT = ws;                        // 64*128   = 8192
    float* fc1T = kleT + 8192;               // 192*128  = 24576
    float* fc2T = fc1T + 24576;
    float* W1aT = fc2T + 24576;              // 128*128  = 16384
    float* W2aT = W1aT + 16384;
    float* E1i  = W2aT + 16384;              // 128*128  = 16384
    float* E2i  = E1i  + 16384;
    float* es1o = E2i  + 16384;              // 4096*128
    float* es2o = es1o + BATCH * 128;

    k_pre <<<960, 128, 0, stream>>>(kle, W1, W2, fc1_W, fc2_W,
                                    kleT, fc1T, fc2T, W1aT, W2aT, E1i, E2i);
    k_prep<<<BATCH / 8, 256, 0, stream>>>(stu_id, exer_id, student_emb, prompt_stu,
                                          k_diff, s_exer, kleT, fc1T, fc2T,
                                          W1aT, W2aT, fc1_b, fc2_b, es1o, es2o);
    k_main<<<BATCH / 2, 256, 0, stream>>>(es1o, es2o, E1i, E2i, W3, b3, kn_emb, out);
}

// Round 13
// 46.382 us; speedup vs baseline: 1.8608x; 1.0354x over previous
//
#include <hip/hip_runtime.h>
#include <hip/hip_bf16.h>

#define STUN   50000
#define BATCH  4096
#define LOG2E  1.4426950408889634f

__device__ __forceinline__ float fexp2(float x){ return __builtin_amdgcn_exp2f(x); }
__device__ __forceinline__ float frcp (float x){ return __builtin_amdgcn_rcpf(x); }
__device__ __forceinline__ float fsig (float x){ return frcp(1.0f + fexp2(-LOG2E * x)); }

// ---------------------------------------------------------------------------
// K0: transposes + E-matrix precompute. 960 blocks x 128 threads. (r12-proven)
//   kleT  [u=64][idx=128]  = kle[idx][u]
//   fc1T/fc2T [u=192][128] = fcW[idx][u]
//   W1aT/W2aT [u=128][128] = W[idx][u]          (the 'a' half, u<128)
//   E1i/E2i [j4=32][k=128][4] = exp2(-log2e * sum_t kle[k][t]*W[j4*4+c][128+t])
// ---------------------------------------------------------------------------
__global__ __launch_bounds__(128) void k_pre(
    const float* __restrict__ kle,
    const float* __restrict__ W1,
    const float* __restrict__ W2,
    const float* __restrict__ fc1_W,
    const float* __restrict__ fc2_W,
    float* __restrict__ kleT,
    float* __restrict__ fc1T,
    float* __restrict__ fc2T,
    float* __restrict__ W1aT,
    float* __restrict__ W2aT,
    float* __restrict__ E1i,
    float* __restrict__ E2i)
{
    const int bid = blockIdx.x;
    const int t   = threadIdx.x;   // 0..127
    if (bid < 64) {
        const int u = bid;
        kleT[u * 128 + t] = kle[t * 64 + u];
    } else if (bid < 256) {
        const int u = bid - 64;
        fc1T[u * 128 + t] = fc1_W[t * 192 + u];
    } else if (bid < 448) {
        const int u = bid - 256;
        fc2T[u * 128 + t] = fc2_W[t * 192 + u];
    } else if (bid < 576) {
        const int u = bid - 448;
        W1aT[u * 128 + t] = W1[t * 192 + u];
    } else if (bid < 704) {
        const int u = bid - 576;
        W2aT[u * 128 + t] = W2[t * 192 + u];
    } else if (bid < 832) {
        const int j = bid - 704;          // lane t = k
        float acc = 0.f;
        #pragma unroll
        for (int u4 = 0; u4 < 16; ++u4) {
            const float4 kv = *(const float4*)&kle[t * 64 + u4 * 4];
            const float4 wv = *(const float4*)&W1[j * 192 + 128 + u4 * 4];
            acc += kv.x * wv.x + kv.y * wv.y + kv.z * wv.z + kv.w * wv.w;
        }
        E1i[((j >> 2) * 128 + t) * 4 + (j & 3)] = fexp2(-LOG2E * acc);
    } else {
        const int j = bid - 832;
        float acc = 0.f;
        #pragma unroll
        for (int u4 = 0; u4 < 16; ++u4) {
            const float4 kv = *(const float4*)&kle[t * 64 + u4 * 4];
            const float4 wv = *(const float4*)&W2[j * 192 + 128 + u4 * 4];
            acc += kv.x * wv.x + kv.y * wv.y + kv.z * wv.z + kv.w * wv.w;
        }
        E2i[((j >> 2) * 128 + t) * 4 + (j & 3)] = fexp2(-LOG2E * acc);
    }
}

// ---------------------------------------------------------------------------
// K_FUSED v6: idx-blocked prep (r12 structure, BBP=4) + LDS-es + r8 main loop.
// 4 batch elems/block, 256 threads, grid 1024 -> 4 blocks/CU (LDS ~38 KB).
// Prep: wave wv = u-quarter; lane: half=l>>5, iq=l&31 (4 idx each).
//       Partials via ps[]; combine thread (ch,cidx); es -> LDS ses.
// Main: t -> k=t&127, bh=t>>7 (b-pair); thread: 2 b x 128 j x 1 k.
//       u = es1*E1, v = es2*E2, acc += (v-u)*rcp((1+u)(1+v))*w3.
// ---------------------------------------------------------------------------
__global__ __launch_bounds__(256, 4) void k_fused(
    const int*   __restrict__ stu_id,
    const int*   __restrict__ exer_id,
    const float* __restrict__ student_emb,   // (2*50000, 64) flat
    const float* __restrict__ prompt_stu,    // (50000, 64)
    const float* __restrict__ k_diff,        // (20000, 64)
    const float* __restrict__ s_exer,        // (2, 64)
    const float* __restrict__ kleT,          // (64,128)
    const float* __restrict__ fc1T,          // (192,128)
    const float* __restrict__ fc2T,
    const float* __restrict__ W1aT,          // (128,128)
    const float* __restrict__ W2aT,
    const float* __restrict__ fc1_b,
    const float* __restrict__ fc2_b,
    const float* __restrict__ E1i,           // [j4=32][k=128][4]
    const float* __restrict__ E2i,
    const float* __restrict__ W3,
    const float* __restrict__ b3,
    const float* __restrict__ kn,
    float* __restrict__ out)
{
    __shared__ __align__(16) float sh_in [4][64][4];    //  4 KB [src][u][b]
    __shared__ __align__(16) float sh_old[2][128][4];   //  4 KB
    __shared__ __align__(16) float sh_e  [2][128][4];   //  4 KB
    __shared__ __align__(16) float ps[4][2][32][20];    // 20 KB [ug][half][iq][b*4+c]
    __shared__ __align__(16) float ses[2][4][128];      //  4 KB [mat][b][j]
    __shared__ float r_o[4][2];
    __shared__ float r_k[4][2];

    const int t  = threadIdx.x;           // 0..255
    const int b0 = blockIdx.x * 4;

    // ---- gather: 64 threads per local batch elem, coalesced ----
    {
        const int g   = t >> 6;
        const int u   = t & 63;
        const int sid = stu_id[b0 + g];
        const int eid = exer_id[b0 + g];
        const int er  = (eid >= 10000) ? 1 : 0;
        sh_in[0][u][g] = student_emb[sid * 64 + u];
        sh_in[1][u][g] = fsig(k_diff[eid * 64 + u]);
        sh_in[2][u][g] = prompt_stu[(sid % STUN) * 64 + u];
        sh_in[3][u][g] = fsig(s_exer[er * 64 + u]);
    }
    __syncthreads();

    const int wv   = t >> 6;              // u-quarter (wave id)
    const int l    = t & 63;
    const int half = l >> 5;
    const int iq   = l & 31;              // idx quad base: idx = iq*4+c
    float* myps = &ps[wv][half][iq][0];

    // combine-phase mapping (all 256 threads)
    const int ch   = t >> 7;
    const int cidx = t & 127;
    const int ciq  = cidx >> 2;
    const int cc   = cidx & 3;

    float a[4][4];

#define CLR { _Pragma("unroll") for (int c = 0; c < 4; ++c) \
              _Pragma("unroll") for (int b = 0; b < 4; ++b) a[c][b] = 0.f; }

#define FMAC(c, wc) { \
    a[c][0] = fmaf(wc, x0.x, a[c][0]); a[c][1] = fmaf(wc, x0.y, a[c][1]); \
    a[c][2] = fmaf(wc, x0.z, a[c][2]); a[c][3] = fmaf(wc, x0.w, a[c][3]); }

#define GSTEP(wp, xp) { \
    const float4 w4 = *(const float4*)(wp); \
    const float4 x0 = *(const float4*)&(xp)[0]; \
    FMAC(0, w4.x); FMAC(1, w4.y); FMAC(2, w4.z); FMAC(3, w4.w); }

#define PSTORE { _Pragma("unroll") for (int b = 0; b < 4; ++b) \
    *(float4*)&myps[b * 4] = make_float4(a[0][b], a[1][b], a[2][b], a[3][b]); }

#define PCOMB(res) float res[4]; \
    _Pragma("unroll") for (int b = 0; b < 4; ++b) \
        res[b] = ps[0][ch][ciq][b * 4 + cc] + ps[1][ch][ciq][b * 4 + cc] \
               + ps[2][ch][ciq][b * 4 + cc] + ps[3][ch][ciq][b * 4 + cc];

    // ---- stage 1: old[idx] = sig( dot64(x_row, kle[idx]) ) ----
    CLR;
    {
        const int u0 = wv * 16;
        #pragma unroll 4
        for (int u = u0; u < u0 + 16; ++u)
            GSTEP(&kleT[u * 128 + iq * 4], sh_in[half][u]);
    }
    PSTORE;
    __syncthreads();
    {
        PCOMB(s);
        #pragma unroll
        for (int b = 0; b < 4; ++b) sh_old[ch][cidx][b] = fsig(s[b]);
    }
    __syncthreads();

    // ---- stage 2: e[idx] = sig( [p, old] @ fcW[idx] + fcb[idx] ) ----
    CLR;
    {
        const float* fcT = half ? fc2T : fc1T;
        const int u0 = wv * 48;
        const int ue_in = (u0 + 48 < 64) ? u0 + 48 : 64;
        #pragma unroll 4
        for (int u = u0; u < ue_in; ++u)
            GSTEP(&fcT[u * 128 + iq * 4], sh_in[2 + half][u]);
        const int us_old = (u0 > 64) ? u0 : 64;
        #pragma unroll 4
        for (int u = us_old; u < u0 + 48; ++u)
            GSTEP(&fcT[u * 128 + iq * 4], sh_old[half][u - 64]);
    }
    PSTORE;
    __syncthreads();
    {
        PCOMB(s);
        const float bias = (ch ? fc2_b : fc1_b)[cidx];
        #pragma unroll
        for (int b = 0; b < 4; ++b) sh_e[ch][cidx][b] = fsig(s[b] + bias);
    }
    __syncthreads();

    // ---- stage 3: ses[mat][b][idx] = exp2( -log2e * dot128(e, Wa[idx]) ) ----
    CLR;
    {
        const float* WT = half ? W2aT : W1aT;
        const int u0 = wv * 32;
        #pragma unroll 4
        for (int u = u0; u < u0 + 32; ++u)
            GSTEP(&WT[u * 128 + iq * 4], sh_e[half][u]);
    }
    PSTORE;
    __syncthreads();
    {
        PCOMB(s);
        #pragma unroll
        for (int b = 0; b < 4; ++b)
            ses[ch][b][cidx] = fexp2(-LOG2E * s[b]);
    }
#undef CLR
#undef FMAC
#undef GSTEP
#undef PSTORE
#undef PCOMB
    __syncthreads();

    // ---- main loop: t -> k = t&127, bh = t>>7; 2 b x 128 j ----
    const int k  = t & 127;
    const int bh = t >> 7;
    const int i0 = bh * 2;

    const float4* E1v = (const float4*)E1i + k;
    const float4* E2v = (const float4*)E2i + k;

    float acc0 = 0.f, acc1 = 0.f;

#define COMP(acc, esv1, esv2, e1c, e2c, w3c) { \
        const float uu = (esv1) * (e1c); \
        const float vv = (esv2) * (e2c); \
        const float dd = frcp((1.f + uu) * (1.f + vv)); \
        acc = fmaf((vv - uu) * dd, (w3c), acc); }

    #pragma unroll 4
    for (int j4 = 0; j4 < 32; ++j4) {
        const int j = j4 * 4;
        const float4 e1  = E1v[j4 * 128];
        const float4 e2  = E2v[j4 * 128];
        const float4 w3  = *(const float4*)&W3[j];
        const float4 p1a = *(const float4*)&ses[0][i0 + 0][j];
        const float4 p2a = *(const float4*)&ses[1][i0 + 0][j];
        const float4 p1b = *(const float4*)&ses[0][i0 + 1][j];
        const float4 p2b = *(const float4*)&ses[1][i0 + 1][j];
        COMP(acc0, p1a.x, p2a.x, e1.x, e2.x, w3.x);
        COMP(acc0, p1a.y, p2a.y, e1.y, e2.y, w3.y);
        COMP(acc0, p1a.z, p2a.z, e1.z, e2.z, w3.z);
        COMP(acc0, p1a.w, p2a.w, e1.w, e2.w, w3.w);
        COMP(acc1, p1b.x, p2b.x, e1.x, e2.x, w3.x);
        COMP(acc1, p1b.y, p2b.y, e1.y, e2.y, w3.y);
        COMP(acc1, p1b.z, p2b.z, e1.z, e2.z, w3.z);
        COMP(acc1, p1b.w, p2b.w, e1.w, e2.w, w3.w);
    }
#undef COMP

    // ---- epilogue: outer sigmoid + kn-weighted mean over k ----
    const float bb3 = b3[0];
    const float o0  = fsig(acc0 + bb3);
    const float o1  = fsig(acc1 + bb3);
    const float kn0 = kn[(b0 + i0 + 0) * 128 + k];
    const float kn1 = kn[(b0 + i0 + 1) * 128 + k];
    float co0 = o0 * kn0, ck0 = kn0;
    float co1 = o1 * kn1, ck1 = kn1;
    #pragma unroll
    for (int off = 1; off < 64; off <<= 1) {
        co0 += __shfl_xor(co0, off);
        ck0 += __shfl_xor(ck0, off);
        co1 += __shfl_xor(co1, off);
        ck1 += __shfl_xor(ck1, off);
    }
    const int w = t >> 6;
    if ((t & 63) == 0) {
        r_o[w][0] = co0; r_o[w][1] = co1;
        r_k[w][0] = ck0; r_k[w][1] = ck1;
    }
    __syncthreads();
    if (t < 4) {
        const int bhh = t >> 1;           // b-pair
        const int i   = t & 1;
        const float so = r_o[bhh * 2][i] + r_o[bhh * 2 + 1][i];
        const float sk = r_k[bhh * 2][i] + r_k[bhh * 2 + 1][i];
        out[b0 + bhh * 2 + i] = so / sk;
    }
}

// ---------------------------------------------------------------------------
extern "C" void kernel_launch(void* const* d_in, const int* in_sizes, int n_in,
                              void* d_out, int out_size, void* d_ws, size_t ws_size,
                              hipStream_t stream)
{
    const int*   stu_id      = (const int*)  d_in[0];
    const int*   exer_id     = (const int*)  d_in[1];
    const float* kn_emb      = (const float*)d_in[2];
    const float* student_emb = (const float*)d_in[3];
    const float* prompt_stu  = (const float*)d_in[4];
    const float* kle         = (const float*)d_in[5];
    const float* k_diff      = (const float*)d_in[6];
    const float* s_exer      = (const float*)d_in[7];
    const float* W1          = (const float*)d_in[8];
    const float* W2          = (const float*)d_in[9];
    const float* W3          = (const float*)d_in[10];
    const float* b3          = (const float*)d_in[11];
    const float* fc1_W       = (const float*)d_in[12];
    const float* fc1_b       = (const float*)d_in[13];
    const float* fc2_W       = (const float*)d_in[14];
    const float* fc2_b       = (const float*)d_in[15];
    float* out = (float*)d_out;

    float* ws   = (float*)d_ws;
    float* kleT = ws;                        // 64*128   = 8192
    float* fc1T = kleT + 8192;               // 192*128  = 24576
    float* fc2T = fc1T + 24576;
    float* W1aT = fc2T + 24576;              // 128*128  = 16384
    float* W2aT = W1aT + 16384;
    float* E1i  = W2aT + 16384;              // 128*128  = 16384
    float* E2i  = E1i  + 16384;

    k_pre  <<<960, 128, 0, stream>>>(kle, W1, W2, fc1_W, fc2_W,
                                     kleT, fc1T, fc2T, W1aT, W2aT, E1i, E2i);
    k_fused<<<BATCH / 4, 256, 0, stream>>>(stu_id, exer_id, student_emb, prompt_stu,
                                           k_diff, s_exer, kleT, fc1T, fc2T,
                                           W1aT, W2aT, fc1_b, fc2_b,
                                           E1i, E2i, W3, b3, kn_emb, out);
}